// Round 11
// baseline (7721.301 us; speedup 1.0000x reference)
//
#include <hip/hip_runtime.h>
#include <hip/hip_cooperative_groups.h>

namespace cg = cooperative_groups;

typedef unsigned short u16;
typedef __attribute__((ext_vector_type(8))) short short8;
typedef __attribute__((ext_vector_type(4))) float f32x4;

#define BATCH 256
#define N0    512
#define N1    2048
#define NIN   4096
#define TSTEPS 60

static __device__ __forceinline__ f32x4 MFMA(short8 a, short8 b, f32x4 c) {
    return __builtin_amdgcn_mfma_f32_16x16x32_bf16(a, b, c, 0, 0, 0);
}

static __device__ __forceinline__ void split1(float x, u16* __restrict__ hp, u16* __restrict__ lp) {
    unsigned bx = __float_as_uint(x);
    *hp = (u16)(bx >> 16);
    float lf = x - __uint_as_float(bx & 0xFFFF0000u);
    *lp = (u16)(__float_as_uint(lf) >> 16);
}

static __device__ __forceinline__ float clamp01(float v) {
    return fminf(fmaxf(v, 0.0f), 1.0f);
}

// Packed fragment-order index for a [R x K] operand, 16x16x32 MFMA frags.
static __device__ __forceinline__ size_t apos(int row, int col, int KT) {
    return ((size_t)((row >> 4) * KT + (col >> 5)) * 64
            + (size_t)((row & 15) | (((col >> 3) & 3) << 4))) * 8 + (col & 7);
}

// Dest-order pack: thread g produces packed elems [g*8, g*8+8).
static __device__ __forceinline__ void pack_tiles(
    const float* __restrict__ src, u16* __restrict__ dsth, u16* __restrict__ dstl,
    int n8, int ktlog, int K, int tid, int nth)
{
    for (int g = tid; g < n8; g += nth) {
        const int t = g >> 6, lane = g & 63;
        const int rt = t >> ktlog, kt = t & ((1 << ktlog) - 1);
        const int row = rt * 16 + (lane & 15);
        const int col = kt * 32 + ((lane >> 4) << 3);
        const float* s = src + (size_t)row * K + col;
        const float4 x0 = *(const float4*)s;
        const float4 x1 = *(const float4*)(s + 4);
        float xs[8] = {x0.x, x0.y, x0.z, x0.w, x1.x, x1.y, x1.z, x1.w};
        union { short8 v; unsigned u[4]; } H, L;
        #pragma unroll
        for (int j = 0; j < 4; ++j) {
            unsigned ba = __float_as_uint(xs[2*j]);
            unsigned bb = __float_as_uint(xs[2*j+1]);
            H.u[j] = (ba >> 16) | (bb & 0xFFFF0000u);
            float la = xs[2*j]   - __uint_as_float(ba & 0xFFFF0000u);
            float lb = xs[2*j+1] - __uint_as_float(bb & 0xFFFF0000u);
            L.u[j] = (__float_as_uint(la) >> 16) | (__float_as_uint(lb) & 0xFFFF0000u);
        }
        *(short8*)(dsth + (size_t)g * 8) = H.v;
        *(short8*)(dstl + (size_t)g * 8) = L.v;
    }
}

// -------- prep --------
__global__ __launch_bounds__(256) void prep_kernel(
    const float* __restrict__ w0, const float* __restrict__ w1,
    const float* __restrict__ w2, const float* __restrict__ data,
    const float* __restrict__ s0, const float* __restrict__ s1,
    u16* __restrict__ w0h, u16* __restrict__ w0l,
    u16* __restrict__ w1h, u16* __restrict__ w1l,
    u16* __restrict__ w2h, u16* __restrict__ w2l,
    u16* __restrict__ dh,  u16* __restrict__ dl,
    float* __restrict__ s0f, float* __restrict__ s1f,
    u16* __restrict__ s0h, u16* __restrict__ s0l,
    u16* __restrict__ s1h, u16* __restrict__ s1l)
{
    const int tid = blockIdx.x * 256 + threadIdx.x;
    const int nth = gridDim.x * 256;
    pack_tiles(w0,   w0h, w0l, N0 * N1 / 8,     6, N1,  tid, nth);  // KT=64
    pack_tiles(w1,   w1h, w1l, N1 * N0 / 8,     4, N0,  tid, nth);  // KT=16
    pack_tiles(w2,   w2h, w2l, N1 * NIN / 8,    7, NIN, tid, nth);  // KT=128
    pack_tiles(data, dh,  dl,  BATCH * NIN / 8, 7, NIN, tid, nth);  // KT=128
    pack_tiles(s0,   s0h, s0l, BATCH * N0 / 8,  4, N0,  tid, nth);  // KT=16
    pack_tiles(s1,   s1h, s1l, BATCH * N1 / 8,  6, N1,  tid, nth);  // KT=64
    for (int i = tid; i < BATCH * N0 / 4; i += nth)
        ((float4*)s0f)[i] = ((const float4*)s0)[i];
    for (int i = tid; i < BATCH * N1 / 4; i += nth)
        ((float4*)s1f)[i] = ((const float4*)s1)[i];
}

// -------- inp1 partials: data @ w2^T (unchanged from R7) --------
__global__ __launch_bounds__(512, 2) void inp1_kernel(
    const u16* __restrict__ dh, const u16* __restrict__ dl,
    const u16* __restrict__ w2h, const u16* __restrict__ w2l,
    float* __restrict__ partial)   // [4][256][2048]
{
    const int wave = threadIdx.x >> 6, lane = threadIdx.x & 63;
    const int lrow = lane & 15, lr4 = (lane >> 4) << 2;
    const int b = blockIdx.x;
    const int chunk = b >> 7, rem = b & 127;
    const int mt = rem >> 5, nt = rem & 31;
    const int wm = wave >> 1, wn = wave & 1;
    const int fm = mt * 4 + wm;
    const int fn0 = nt * 4 + wn * 2;
    const int kt0 = chunk * 32;

    const u16* pah = dh  + ((size_t)(fm  * 128 + kt0) * 64 + lane) * 8;
    const u16* pal = dl  + ((size_t)(fm  * 128 + kt0) * 64 + lane) * 8;
    const u16* pb0h = w2h + ((size_t)(fn0 * 128 + kt0) * 64 + lane) * 8;
    const u16* pb0l = w2l + ((size_t)(fn0 * 128 + kt0) * 64 + lane) * 8;
    const u16* pb1h = pb0h + (size_t)128 * 512;
    const u16* pb1l = pb0l + (size_t)128 * 512;

    f32x4 acc[2][3] = {};
    #pragma unroll 4
    for (int i = 0; i < 32; ++i) {
        const int off = i * 512;
        short8 ah = *(const short8*)(pah + off);
        short8 al = *(const short8*)(pal + off);
        short8 b0h_ = *(const short8*)(pb0h + off);
        short8 b0l_ = *(const short8*)(pb0l + off);
        short8 b1h_ = *(const short8*)(pb1h + off);
        short8 b1l_ = *(const short8*)(pb1l + off);
        acc[0][0] = MFMA(ah, b0h_, acc[0][0]);
        acc[0][1] = MFMA(ah, b0l_, acc[0][1]);
        acc[0][2] = MFMA(al, b0h_, acc[0][2]);
        acc[1][0] = MFMA(ah, b1h_, acc[1][0]);
        acc[1][1] = MFMA(ah, b1l_, acc[1][1]);
        acc[1][2] = MFMA(al, b1h_, acc[1][2]);
    }
    float* out = partial + (size_t)chunk * BATCH * N1;
    #pragma unroll
    for (int n = 0; n < 2; ++n) {
        const int col = nt * 64 + wn * 32 + n * 16 + lrow;
        #pragma unroll
        for (int r = 0; r < 4; ++r) {
            const int row = mt * 64 + wm * 16 + lr4 + r;
            out[(size_t)row * N1 + col] = acc[n][0][r] + acc[n][1][r] + acc[n][2][r];
        }
    }
}

__global__ __launch_bounds__(256) void reduce_kernel(
    const float* __restrict__ partial, const float* __restrict__ b2,
    float* __restrict__ inp1)
{
    const int e = blockIdx.x * 256 + threadIdx.x;
    const float4* p0 = (const float4*)partial;
    const float4* p1 = p0 + (BATCH * N1 / 4);
    const float4* p2 = p1 + (BATCH * N1 / 4);
    const float4* p3 = p2 + (BATCH * N1 / 4);
    const float4 b = ((const float4*)b2)[e & (N1 / 4 - 1)];
    float4 a0 = p0[e], a1 = p1[e], a2 = p2[e], a3 = p3[e];
    float4 r;
    r.x = a0.x + a1.x + a2.x + a3.x + b.x;
    r.y = a0.y + a1.y + a2.y + a3.y + b.y;
    r.z = a0.z + a1.z + a2.z + a3.z + b.z;
    r.w = a0.w + a1.w + a2.w + a3.w + b.w;
    ((float4*)inp1)[e] = r;
}

// -------- persistent all-steps kernel --------
// 256 WGs x 512 thr, 1 WG/CU (144KB LDS). Weight slice loaded to LDS once.
// WGs 0..127  (C1): out s1' tile 64 batch x 64 n1-cols; K=512 full per wave pair.
// WGs 128..255(C0): out s0' tile 64 batch x 16 n0-cols; K=2048 wave-split-4 + LDS reduce.
struct PP {
    const u16 *w1h, *w1l, *w0h, *w0l;
    const float *inp1, *b0;
    float *s0f0, *s0f1, *s1f0, *s1f1;
    u16 *s0h0, *s0h1, *s0l0, *s0l1;
    u16 *s1h0, *s1h1, *s1l0, *s1l1;
    float *out_s0, *out_s1;
};

__global__ __launch_bounds__(512, 1) void persist_kernel(PP P)
{
    __shared__ u16 lwh[32768];            // 64 KB weight hi slice
    __shared__ u16 lwl[32768];            // 64 KB weight lo slice
    __shared__ float red[4][64][16];      // 16 KB C0 reduction

    const int b = blockIdx.x;
    const int tid = (int)threadIdx.x;
    const int wave = tid >> 6, lane = tid & 63;
    const int lrow = lane & 15, lr4 = (lane >> 4) << 2;
    const bool isC1 = (b < 128);
    const int mt = isC1 ? (b >> 5) : ((b - 128) >> 5);   // 0..3 batch-64 tile
    const int nt = isC1 ? (b & 31) : ((b - 128) & 31);   // col tile

    // one-time LDS weight load (slices are contiguous in packed layout)
    {
        const short8* gh = (const short8*)((isC1 ? P.w1h : P.w0h) + (size_t)nt * 32768);
        const short8* gl = (const short8*)((isC1 ? P.w1l : P.w0l) + (size_t)nt * 32768);
        short8* dh_ = (short8*)lwh;
        short8* dl_ = (short8*)lwl;
        for (int i = tid; i < 4096; i += 512) { dh_[i] = gh[i]; dl_[i] = gl[i]; }
    }
    __syncthreads();

    cg::grid_group grid = cg::this_grid();

    float *s0f[2] = {P.s0f0, P.s0f1}, *s1f[2] = {P.s1f0, P.s1f1};
    u16 *s0h[2] = {P.s0h0, P.s0h1}, *s0l[2] = {P.s0l0, P.s0l1};
    u16 *s1h[2] = {P.s1h0, P.s1h1}, *s1l[2] = {P.s1l0, P.s1l1};

    for (int t = 0; t < TSTEPS; ++t) {
        const int cur = t & 1, nxt = cur ^ 1;
        const bool last = (t == TSTEPS - 1);
        if (isC1) {
            // ---- C1: s1' = clip(0.5*(s1 + inp1 + s0 @ w1^T)) ----
            const int wm = wave >> 1, wn = (wave & 1) * 2;   // 2 n-frags per wave
            const int fm = mt * 4 + wm;
            const u16* pah = s0h[cur] + ((size_t)(fm * 16) * 64 + lane) * 8;
            const u16* pal = s0l[cur] + ((size_t)(fm * 16) * 64 + lane) * 8;
            const u16* lb  = lwh + (size_t)(wn * 16) * 512 + lane * 8;
            const u16* lbl = lwl + (size_t)(wn * 16) * 512 + lane * 8;

            f32x4 acc[2][3] = {};
            #pragma unroll 4
            for (int kt = 0; kt < 16; ++kt) {
                const int go = kt * 512;
                short8 ah = *(const short8*)(pah + go);
                short8 al = *(const short8*)(pal + go);
                short8 b0h_ = *(const short8*)(lb + go);
                short8 b0l_ = *(const short8*)(lbl + go);
                short8 b1h_ = *(const short8*)(lb + go + 8192);
                short8 b1l_ = *(const short8*)(lbl + go + 8192);
                acc[0][0] = MFMA(ah, b0h_, acc[0][0]);
                acc[0][1] = MFMA(ah, b0l_, acc[0][1]);
                acc[0][2] = MFMA(al, b0h_, acc[0][2]);
                acc[1][0] = MFMA(ah, b1h_, acc[1][0]);
                acc[1][1] = MFMA(ah, b1l_, acc[1][1]);
                acc[1][2] = MFMA(al, b1h_, acc[1][2]);
            }
            const float* s1fi = s1f[cur];
            float* s1fo = last ? P.out_s1 : s1f[nxt];
            u16 *s1ho = s1h[nxt], *s1lo = s1l[nxt];
            #pragma unroll
            for (int n = 0; n < 2; ++n) {
                const int col = nt * 64 + (wn + n) * 16 + lrow;
                #pragma unroll
                for (int r = 0; r < 4; ++r) {
                    const int row = mt * 64 + wm * 16 + lr4 + r;
                    const size_t idx = (size_t)row * N1 + col;
                    const float sum = acc[n][0][r] + acc[n][1][r] + acc[n][2][r];
                    float v = 0.5f * (s1fi[idx] + P.inp1[idx] + sum);
                    v = clamp01(v);
                    s1fo[idx] = v;
                    u16 h, l; split1(v, &h, &l);
                    const size_t p = apos(row, col, 64);
                    s1ho[p] = h; s1lo[p] = l;
                }
            }
        } else {
            // ---- C0: s0' = clip(0.5*(s0 + s1 @ w0^T + b0)) ----
            const int wk = wave >> 1, wm2 = wave & 1;   // k-quarter, m-half
            const int fm0 = mt * 4 + wm2 * 2;
            const u16* pa0h = s1h[cur] + ((size_t)((fm0)     * 64 + wk * 16) * 64 + lane) * 8;
            const u16* pa0l = s1l[cur] + ((size_t)((fm0)     * 64 + wk * 16) * 64 + lane) * 8;
            const u16* pa1h = s1h[cur] + ((size_t)((fm0 + 1) * 64 + wk * 16) * 64 + lane) * 8;
            const u16* pa1l = s1l[cur] + ((size_t)((fm0 + 1) * 64 + wk * 16) * 64 + lane) * 8;
            const u16* lb  = lwh + (size_t)(wk * 16) * 512 + lane * 8;
            const u16* lbl = lwl + (size_t)(wk * 16) * 512 + lane * 8;

            f32x4 acc[2][3] = {};
            #pragma unroll 4
            for (int i = 0; i < 16; ++i) {
                const int go = i * 512;
                short8 ah0 = *(const short8*)(pa0h + go);
                short8 al0 = *(const short8*)(pa0l + go);
                short8 ah1 = *(const short8*)(pa1h + go);
                short8 al1 = *(const short8*)(pa1l + go);
                short8 bh = *(const short8*)(lb + go);
                short8 bl = *(const short8*)(lbl + go);
                acc[0][0] = MFMA(ah0, bh, acc[0][0]);
                acc[0][1] = MFMA(ah0, bl, acc[0][1]);
                acc[0][2] = MFMA(al0, bh, acc[0][2]);
                acc[1][0] = MFMA(ah1, bh, acc[1][0]);
                acc[1][1] = MFMA(ah1, bl, acc[1][1]);
                acc[1][2] = MFMA(al1, bh, acc[1][2]);
            }
            #pragma unroll
            for (int m = 0; m < 2; ++m) {
                const int fr = (wm2 * 2 + m) * 16;
                #pragma unroll
                for (int r = 0; r < 4; ++r)
                    red[wk][fr + lr4 + r][lrow] = acc[m][0][r] + acc[m][1][r] + acc[m][2][r];
            }
            __syncthreads();
            const float* s0fi = s0f[cur];
            float* s0fo = last ? P.out_s0 : s0f[nxt];
            u16 *s0ho = s0h[nxt], *s0lo = s0l[nxt];
            #pragma unroll
            for (int e = tid; e < 1024; e += 512) {
                const int r_ = e >> 4, c_ = e & 15;
                const int row = mt * 64 + r_, col = nt * 16 + c_;
                const float sum = red[0][r_][c_] + red[1][r_][c_]
                                + red[2][r_][c_] + red[3][r_][c_];
                const size_t idx = (size_t)row * N0 + col;
                float v = 0.5f * (s0fi[idx] + sum + P.b0[col]);
                v = clamp01(v);
                s0fo[idx] = v;
                u16 h, l; split1(v, &h, &l);
                const size_t p = apos(row, col, 16);
                s0ho[p] = h; s0lo[p] = l;
            }
        }
        __threadfence();   // release: make this step's stores visible device-wide
        grid.sync();
        __threadfence();   // acquire: don't read stale lines next step
    }
}

extern "C" void kernel_launch(void* const* d_in, const int* in_sizes, int n_in,
                              void* d_out, int out_size, void* d_ws, size_t ws_size,
                              hipStream_t stream) {
    const float* data = (const float*)d_in[0];
    const float* s0_0 = (const float*)d_in[1];
    const float* s1_0 = (const float*)d_in[2];
    const float* w0   = (const float*)d_in[3];
    const float* b0   = (const float*)d_in[4];
    const float* w1   = (const float*)d_in[5];
    const float* w2   = (const float*)d_in[6];
    const float* b2   = (const float*)d_in[7];

    char* p = (char*)d_ws;
    auto alloc = [&](size_t bytes) -> char* {
        char* r = p;
        p += (bytes + 255) & ~(size_t)255;
        return r;
    };
    u16* w0h = (u16*)alloc(N0 * N1 * sizeof(u16));
    u16* w0l = (u16*)alloc(N0 * N1 * sizeof(u16));
    u16* w1h = (u16*)alloc(N0 * N1 * sizeof(u16));
    u16* w1l = (u16*)alloc(N0 * N1 * sizeof(u16));
    u16* w2h = (u16*)alloc((size_t)N1 * NIN * sizeof(u16));
    u16* w2l = (u16*)alloc((size_t)N1 * NIN * sizeof(u16));
    u16* dh  = (u16*)alloc((size_t)BATCH * NIN * sizeof(u16));
    u16* dl  = (u16*)alloc((size_t)BATCH * NIN * sizeof(u16));
    float* partial = (float*)alloc((size_t)4 * BATCH * N1 * sizeof(float));
    float* inp1 = (float*)alloc((size_t)BATCH * N1 * sizeof(float));
    float* s0f[2], *s1f[2];
    u16 *s0h[2], *s0l[2], *s1h[2], *s1l[2];
    for (int i = 0; i < 2; ++i) {
        s0f[i] = (float*)alloc((size_t)BATCH * N0 * sizeof(float));
        s1f[i] = (float*)alloc((size_t)BATCH * N1 * sizeof(float));
        s0h[i] = (u16*)alloc((size_t)BATCH * N0 * sizeof(u16));
        s0l[i] = (u16*)alloc((size_t)BATCH * N0 * sizeof(u16));
        s1h[i] = (u16*)alloc((size_t)BATCH * N1 * sizeof(u16));
        s1l[i] = (u16*)alloc((size_t)BATCH * N1 * sizeof(u16));
    }

    prep_kernel<<<2048, 256, 0, stream>>>(w0, w1, w2, data, s0_0, s1_0,
                                          w0h, w0l, w1h, w1l, w2h, w2l, dh, dl,
                                          s0f[0], s1f[0], s0h[0], s0l[0], s1h[0], s1l[0]);

    inp1_kernel<<<512, 512, 0, stream>>>(dh, dl, w2h, w2l, partial);
    reduce_kernel<<<BATCH * N1 / 4 / 256, 256, 0, stream>>>(partial, b2, inp1);

    PP pp;
    pp.w1h = w1h; pp.w1l = w1l; pp.w0h = w0h; pp.w0l = w0l;
    pp.inp1 = inp1; pp.b0 = b0;
    pp.s0f0 = s0f[0]; pp.s0f1 = s0f[1]; pp.s1f0 = s1f[0]; pp.s1f1 = s1f[1];
    pp.s0h0 = s0h[0]; pp.s0h1 = s0h[1]; pp.s0l0 = s0l[0]; pp.s0l1 = s0l[1];
    pp.s1h0 = s1h[0]; pp.s1h1 = s1h[1]; pp.s1l0 = s1l[0]; pp.s1l1 = s1l[1];
    pp.out_s0 = (float*)d_out;
    pp.out_s1 = (float*)d_out + (size_t)BATCH * N0;

    void* args[] = { &pp };
    hipLaunchCooperativeKernel((const void*)persist_kernel,
                               dim3(256), dim3(512), args, 0, stream);
}

// Round 15
// 7377.663 us; speedup vs baseline: 1.0466x; 1.0466x over previous
//
#include <hip/hip_runtime.h>

typedef unsigned short u16;
typedef unsigned int u32;
typedef __attribute__((ext_vector_type(8))) short short8;
typedef __attribute__((ext_vector_type(4))) float f32x4;

#define BATCH 256
#define N0    512
#define N1    2048
#define NIN   4096
#define TSTEPS 60

static __device__ __forceinline__ f32x4 MFMA(short8 a, short8 b, f32x4 c) {
    return __builtin_amdgcn_mfma_f32_16x16x32_bf16(a, b, c, 0, 0, 0);
}

static __device__ __forceinline__ void split1(float x, u16* __restrict__ hp, u16* __restrict__ lp) {
    unsigned bx = __float_as_uint(x);
    *hp = (u16)(bx >> 16);
    float lf = x - __uint_as_float(bx & 0xFFFF0000u);
    *lp = (u16)(__float_as_uint(lf) >> 16);
}

static __device__ __forceinline__ float clamp01(float v) {
    return fminf(fmaxf(v, 0.0f), 1.0f);
}

// Packed fragment-order index for a [R x K] operand, 16x16x32 MFMA frags.
static __device__ __forceinline__ size_t apos(int row, int col, int KT) {
    return ((size_t)((row >> 4) * KT + (col >> 5)) * 64
            + (size_t)((row & 15) | (((col >> 3) & 3) << 4))) * 8 + (col & 7);
}

// Dest-order pack: thread g produces packed elems [g*8, g*8+8).
static __device__ __forceinline__ void pack_tiles(
    const float* __restrict__ src, u16* __restrict__ dsth, u16* __restrict__ dstl,
    int n8, int ktlog, int K, int tid, int nth)
{
    for (int g = tid; g < n8; g += nth) {
        const int t = g >> 6, lane = g & 63;
        const int rt = t >> ktlog, kt = t & ((1 << ktlog) - 1);
        const int row = rt * 16 + (lane & 15);
        const int col = kt * 32 + ((lane >> 4) << 3);
        const float* s = src + (size_t)row * K + col;
        const float4 x0 = *(const float4*)s;
        const float4 x1 = *(const float4*)(s + 4);
        float xs[8] = {x0.x, x0.y, x0.z, x0.w, x1.x, x1.y, x1.z, x1.w};
        union { short8 v; unsigned u[4]; } H, L;
        #pragma unroll
        for (int j = 0; j < 4; ++j) {
            unsigned ba = __float_as_uint(xs[2*j]);
            unsigned bb = __float_as_uint(xs[2*j+1]);
            H.u[j] = (ba >> 16) | (bb & 0xFFFF0000u);
            float la = xs[2*j]   - __uint_as_float(ba & 0xFFFF0000u);
            float lb = xs[2*j+1] - __uint_as_float(bb & 0xFFFF0000u);
            L.u[j] = (__float_as_uint(la) >> 16) | (__float_as_uint(lb) & 0xFFFF0000u);
        }
        *(short8*)(dsth + (size_t)g * 8) = H.v;
        *(short8*)(dstl + (size_t)g * 8) = L.v;
    }
}

// -------- prep (also zeroes barrier state) --------
__global__ __launch_bounds__(256) void prep_kernel(
    const float* __restrict__ w0, const float* __restrict__ w1,
    const float* __restrict__ w2, const float* __restrict__ data,
    const float* __restrict__ s0, const float* __restrict__ s1,
    u16* __restrict__ w0h, u16* __restrict__ w0l,
    u16* __restrict__ w1h, u16* __restrict__ w1l,
    u16* __restrict__ w2h, u16* __restrict__ w2l,
    u16* __restrict__ dh,  u16* __restrict__ dl,
    float* __restrict__ s0f, float* __restrict__ s1f,
    u16* __restrict__ s0h, u16* __restrict__ s0l,
    u16* __restrict__ s1h, u16* __restrict__ s1l,
    u32* __restrict__ bar)   // arrive[256*32] + epoch
{
    const int tid = blockIdx.x * 256 + threadIdx.x;
    const int nth = gridDim.x * 256;
    for (int i = tid; i < 256 * 32 + 32; i += nth) bar[i] = 0;
    pack_tiles(w0,   w0h, w0l, N0 * N1 / 8,     6, N1,  tid, nth);  // KT=64
    pack_tiles(w1,   w1h, w1l, N1 * N0 / 8,     4, N0,  tid, nth);  // KT=16
    pack_tiles(w2,   w2h, w2l, N1 * NIN / 8,    7, NIN, tid, nth);  // KT=128
    pack_tiles(data, dh,  dl,  BATCH * NIN / 8, 7, NIN, tid, nth);  // KT=128
    pack_tiles(s0,   s0h, s0l, BATCH * N0 / 8,  4, N0,  tid, nth);  // KT=16
    pack_tiles(s1,   s1h, s1l, BATCH * N1 / 8,  6, N1,  tid, nth);  // KT=64
    for (int i = tid; i < BATCH * N0 / 4; i += nth)
        ((float4*)s0f)[i] = ((const float4*)s0)[i];
    for (int i = tid; i < BATCH * N1 / 4; i += nth)
        ((float4*)s1f)[i] = ((const float4*)s1)[i];
}

// -------- inp1 partials: data @ w2^T --------
__global__ __launch_bounds__(512, 2) void inp1_kernel(
    const u16* __restrict__ dh, const u16* __restrict__ dl,
    const u16* __restrict__ w2h, const u16* __restrict__ w2l,
    float* __restrict__ partial)   // [4][256][2048]
{
    const int wave = threadIdx.x >> 6, lane = threadIdx.x & 63;
    const int lrow = lane & 15, lr4 = (lane >> 4) << 2;
    const int b = blockIdx.x;
    const int chunk = b >> 7, rem = b & 127;
    const int mt = rem >> 5, nt = rem & 31;
    const int wm = wave >> 1, wn = wave & 1;
    const int fm = mt * 4 + wm;
    const int fn0 = nt * 4 + wn * 2;
    const int kt0 = chunk * 32;

    const u16* pah = dh  + ((size_t)(fm  * 128 + kt0) * 64 + lane) * 8;
    const u16* pal = dl  + ((size_t)(fm  * 128 + kt0) * 64 + lane) * 8;
    const u16* pb0h = w2h + ((size_t)(fn0 * 128 + kt0) * 64 + lane) * 8;
    const u16* pb0l = w2l + ((size_t)(fn0 * 128 + kt0) * 64 + lane) * 8;
    const u16* pb1h = pb0h + (size_t)128 * 512;
    const u16* pb1l = pb0l + (size_t)128 * 512;

    f32x4 acc[2][3] = {};
    #pragma unroll 4
    for (int i = 0; i < 32; ++i) {
        const int off = i * 512;
        short8 ah = *(const short8*)(pah + off);
        short8 al = *(const short8*)(pal + off);
        short8 b0h_ = *(const short8*)(pb0h + off);
        short8 b0l_ = *(const short8*)(pb0l + off);
        short8 b1h_ = *(const short8*)(pb1h + off);
        short8 b1l_ = *(const short8*)(pb1l + off);
        acc[0][0] = MFMA(ah, b0h_, acc[0][0]);
        acc[0][1] = MFMA(ah, b0l_, acc[0][1]);
        acc[0][2] = MFMA(al, b0h_, acc[0][2]);
        acc[1][0] = MFMA(ah, b1h_, acc[1][0]);
        acc[1][1] = MFMA(ah, b1l_, acc[1][1]);
        acc[1][2] = MFMA(al, b1h_, acc[1][2]);
    }
    float* out = partial + (size_t)chunk * BATCH * N1;
    #pragma unroll
    for (int n = 0; n < 2; ++n) {
        const int col = nt * 64 + wn * 32 + n * 16 + lrow;
        #pragma unroll
        for (int r = 0; r < 4; ++r) {
            const int row = mt * 64 + wm * 16 + lr4 + r;
            out[(size_t)row * N1 + col] = acc[n][0][r] + acc[n][1][r] + acc[n][2][r];
        }
    }
}

__global__ __launch_bounds__(256) void reduce_kernel(
    const float* __restrict__ partial, const float* __restrict__ b2,
    float* __restrict__ inp1)
{
    const int e = blockIdx.x * 256 + threadIdx.x;
    const float4* p0 = (const float4*)partial;
    const float4* p1 = p0 + (BATCH * N1 / 4);
    const float4* p2 = p1 + (BATCH * N1 / 4);
    const float4* p3 = p2 + (BATCH * N1 / 4);
    const float4 b = ((const float4*)b2)[e & (N1 / 4 - 1)];
    float4 a0 = p0[e], a1 = p1[e], a2 = p2[e], a3 = p3[e];
    float4 r;
    r.x = a0.x + a1.x + a2.x + a3.x + b.x;
    r.y = a0.y + a1.y + a2.y + a3.y + b.y;
    r.z = a0.z + a1.z + a2.z + a3.z + b.z;
    r.w = a0.w + a1.w + a2.w + a3.w + b.w;
    ((float4*)inp1)[e] = r;
}

// -------- persistent all-steps kernel (custom agent-scope barrier) --------
struct PP {
    const u16 *w1h, *w1l, *w0h, *w0l;
    const float *inp1, *b0;
    float *s0f0, *s0f1, *s1f0, *s1f1;
    u16 *s0h0, *s0h1, *s0l0, *s0l1;
    u16 *s1h0, *s1h1, *s1l0, *s1l1;
    float *out_s0, *out_s1;
    u32 *arrive;   // 256 slots, stride 32 u32 (128B)
    u32 *epoch;    // 1 slot
};

// Sense-free monotonic barrier: WG b stores t+1 to arrive[b]; WG 0 sweeps
// (255 threads in parallel), then release-stores epoch=t+1; others spin.
static __device__ __forceinline__ void grid_barrier(const PP& P, int bid, int tid, u32 t1)
{
    __threadfence();                 // release: drain + L2 writeback
    __syncthreads();
    if (bid == 0) {
        if (tid >= 1 && tid < 256) {
            while (__hip_atomic_load(&P.arrive[tid * 32], __ATOMIC_RELAXED,
                                     __HIP_MEMORY_SCOPE_AGENT) < t1)
                __builtin_amdgcn_s_sleep(2);
        }
        __syncthreads();
        if (tid == 0)
            __hip_atomic_store(P.epoch, t1, __ATOMIC_RELEASE, __HIP_MEMORY_SCOPE_AGENT);
    } else {
        if (tid == 0) {
            __hip_atomic_store(&P.arrive[bid * 32], t1, __ATOMIC_RELAXED,
                               __HIP_MEMORY_SCOPE_AGENT);
            while (__hip_atomic_load(P.epoch, __ATOMIC_ACQUIRE,
                                     __HIP_MEMORY_SCOPE_AGENT) < t1)
                __builtin_amdgcn_s_sleep(2);
        }
    }
    __syncthreads();
    __threadfence();                 // acquire: L2 invalidate before fresh reads
}

__global__ __launch_bounds__(512, 1) void persist_kernel(PP P)
{
    __shared__ u16 lwh[32768];            // 64 KB weight hi slice
    __shared__ u16 lwl[32768];            // 64 KB weight lo slice
    __shared__ float red[4][64][16];      // 16 KB C0 reduction

    const int b = blockIdx.x;
    const int tid = (int)threadIdx.x;
    const int wave = tid >> 6, lane = tid & 63;
    const int lrow = lane & 15, lr4 = (lane >> 4) << 2;
    const bool isC1 = (b < 128);
    const int mt = isC1 ? (b >> 5) : ((b - 128) >> 5);
    const int nt = isC1 ? (b & 31) : ((b - 128) & 31);

    {
        const short8* gh = (const short8*)((isC1 ? P.w1h : P.w0h) + (size_t)nt * 32768);
        const short8* gl = (const short8*)((isC1 ? P.w1l : P.w0l) + (size_t)nt * 32768);
        short8* dh_ = (short8*)lwh;
        short8* dl_ = (short8*)lwl;
        for (int i = tid; i < 4096; i += 512) { dh_[i] = gh[i]; dl_[i] = gl[i]; }
    }
    __syncthreads();

    float *s0f[2] = {P.s0f0, P.s0f1}, *s1f[2] = {P.s1f0, P.s1f1};
    u16 *s0h[2] = {P.s0h0, P.s0h1}, *s0l[2] = {P.s0l0, P.s0l1};
    u16 *s1h[2] = {P.s1h0, P.s1h1}, *s1l[2] = {P.s1l0, P.s1l1};

    for (int t = 0; t < TSTEPS; ++t) {
        const int cur = t & 1, nxt = cur ^ 1;
        const bool last = (t == TSTEPS - 1);
        if (isC1) {
            const int wm = wave >> 1, wn = (wave & 1) * 2;
            const int fm = mt * 4 + wm;
            const u16* pah = s0h[cur] + ((size_t)(fm * 16) * 64 + lane) * 8;
            const u16* pal = s0l[cur] + ((size_t)(fm * 16) * 64 + lane) * 8;
            const u16* lb  = lwh + (size_t)(wn * 16) * 512 + lane * 8;
            const u16* lbl = lwl + (size_t)(wn * 16) * 512 + lane * 8;

            f32x4 acc[2][3] = {};
            #pragma unroll 4
            for (int kt = 0; kt < 16; ++kt) {
                const int go = kt * 512;
                short8 ah = *(const short8*)(pah + go);
                short8 al = *(const short8*)(pal + go);
                short8 b0h_ = *(const short8*)(lb + go);
                short8 b0l_ = *(const short8*)(lbl + go);
                short8 b1h_ = *(const short8*)(lb + go + 8192);
                short8 b1l_ = *(const short8*)(lbl + go + 8192);
                acc[0][0] = MFMA(ah, b0h_, acc[0][0]);
                acc[0][1] = MFMA(ah, b0l_, acc[0][1]);
                acc[0][2] = MFMA(al, b0h_, acc[0][2]);
                acc[1][0] = MFMA(ah, b1h_, acc[1][0]);
                acc[1][1] = MFMA(ah, b1l_, acc[1][1]);
                acc[1][2] = MFMA(al, b1h_, acc[1][2]);
            }
            const float* s1fi = s1f[cur];
            float* s1fo = last ? P.out_s1 : s1f[nxt];
            u16 *s1ho = s1h[nxt], *s1lo = s1l[nxt];
            #pragma unroll
            for (int n = 0; n < 2; ++n) {
                const int col = nt * 64 + (wn + n) * 16 + lrow;
                #pragma unroll
                for (int r = 0; r < 4; ++r) {
                    const int row = mt * 64 + wm * 16 + lr4 + r;
                    const size_t idx = (size_t)row * N1 + col;
                    const float sum = acc[n][0][r] + acc[n][1][r] + acc[n][2][r];
                    float v = 0.5f * (s1fi[idx] + P.inp1[idx] + sum);
                    v = clamp01(v);
                    s1fo[idx] = v;
                    u16 h, l; split1(v, &h, &l);
                    const size_t p = apos(row, col, 64);
                    s1ho[p] = h; s1lo[p] = l;
                }
            }
        } else {
            const int wk = wave >> 1, wm2 = wave & 1;
            const int fm0 = mt * 4 + wm2 * 2;
            const u16* pa0h = s1h[cur] + ((size_t)((fm0)     * 64 + wk * 16) * 64 + lane) * 8;
            const u16* pa0l = s1l[cur] + ((size_t)((fm0)     * 64 + wk * 16) * 64 + lane) * 8;
            const u16* pa1h = s1h[cur] + ((size_t)((fm0 + 1) * 64 + wk * 16) * 64 + lane) * 8;
            const u16* pa1l = s1l[cur] + ((size_t)((fm0 + 1) * 64 + wk * 16) * 64 + lane) * 8;
            const u16* lb  = lwh + (size_t)(wk * 16) * 512 + lane * 8;
            const u16* lbl = lwl + (size_t)(wk * 16) * 512 + lane * 8;

            f32x4 acc[2][3] = {};
            #pragma unroll 4
            for (int i = 0; i < 16; ++i) {
                const int go = i * 512;
                short8 ah0 = *(const short8*)(pa0h + go);
                short8 al0 = *(const short8*)(pa0l + go);
                short8 ah1 = *(const short8*)(pa1h + go);
                short8 al1 = *(const short8*)(pa1l + go);
                short8 bh = *(const short8*)(lb + go);
                short8 bl = *(const short8*)(lbl + go);
                acc[0][0] = MFMA(ah0, bh, acc[0][0]);
                acc[0][1] = MFMA(ah0, bl, acc[0][1]);
                acc[0][2] = MFMA(al0, bh, acc[0][2]);
                acc[1][0] = MFMA(ah1, bh, acc[1][0]);
                acc[1][1] = MFMA(ah1, bl, acc[1][1]);
                acc[1][2] = MFMA(al1, bh, acc[1][2]);
            }
            #pragma unroll
            for (int m = 0; m < 2; ++m) {
                const int fr = (wm2 * 2 + m) * 16;
                #pragma unroll
                for (int r = 0; r < 4; ++r)
                    red[wk][fr + lr4 + r][lrow] = acc[m][0][r] + acc[m][1][r] + acc[m][2][r];
            }
            __syncthreads();
            const float* s0fi = s0f[cur];
            float* s0fo = last ? P.out_s0 : s0f[nxt];
            u16 *s0ho = s0h[nxt], *s0lo = s0l[nxt];
            #pragma unroll
            for (int e = tid; e < 1024; e += 512) {
                const int r_ = e >> 4, c_ = e & 15;
                const int row = mt * 64 + r_, col = nt * 16 + c_;
                const float sum = red[0][r_][c_] + red[1][r_][c_]
                                + red[2][r_][c_] + red[3][r_][c_];
                const size_t idx = (size_t)row * N0 + col;
                float v = 0.5f * (s0fi[idx] + sum + P.b0[col]);
                v = clamp01(v);
                s0fo[idx] = v;
                u16 h, l; split1(v, &h, &l);
                const size_t p = apos(row, col, 16);
                s0ho[p] = h; s0lo[p] = l;
            }
            __syncthreads();   // red[] reuse safety before next step
        }
        if (!last) grid_barrier(P, b, tid, (u32)(t + 1));
    }
}

extern "C" void kernel_launch(void* const* d_in, const int* in_sizes, int n_in,
                              void* d_out, int out_size, void* d_ws, size_t ws_size,
                              hipStream_t stream) {
    const float* data = (const float*)d_in[0];
    const float* s0_0 = (const float*)d_in[1];
    const float* s1_0 = (const float*)d_in[2];
    const float* w0   = (const float*)d_in[3];
    const float* b0   = (const float*)d_in[4];
    const float* w1   = (const float*)d_in[5];
    const float* w2   = (const float*)d_in[6];
    const float* b2   = (const float*)d_in[7];

    char* p = (char*)d_ws;
    auto alloc = [&](size_t bytes) -> char* {
        char* r = p;
        p += (bytes + 255) & ~(size_t)255;
        return r;
    };
    u16* w0h = (u16*)alloc(N0 * N1 * sizeof(u16));
    u16* w0l = (u16*)alloc(N0 * N1 * sizeof(u16));
    u16* w1h = (u16*)alloc(N0 * N1 * sizeof(u16));
    u16* w1l = (u16*)alloc(N0 * N1 * sizeof(u16));
    u16* w2h = (u16*)alloc((size_t)N1 * NIN * sizeof(u16));
    u16* w2l = (u16*)alloc((size_t)N1 * NIN * sizeof(u16));
    u16* dh  = (u16*)alloc((size_t)BATCH * NIN * sizeof(u16));
    u16* dl  = (u16*)alloc((size_t)BATCH * NIN * sizeof(u16));
    float* partial = (float*)alloc((size_t)4 * BATCH * N1 * sizeof(float));
    float* inp1 = (float*)alloc((size_t)BATCH * N1 * sizeof(float));
    u32* bar = (u32*)alloc((256 * 32 + 32) * sizeof(u32));
    float* s0f[2], *s1f[2];
    u16 *s0h[2], *s0l[2], *s1h[2], *s1l[2];
    for (int i = 0; i < 2; ++i) {
        s0f[i] = (float*)alloc((size_t)BATCH * N0 * sizeof(float));
        s1f[i] = (float*)alloc((size_t)BATCH * N1 * sizeof(float));
        s0h[i] = (u16*)alloc((size_t)BATCH * N0 * sizeof(u16));
        s0l[i] = (u16*)alloc((size_t)BATCH * N0 * sizeof(u16));
        s1h[i] = (u16*)alloc((size_t)BATCH * N1 * sizeof(u16));
        s1l[i] = (u16*)alloc((size_t)BATCH * N1 * sizeof(u16));
    }

    prep_kernel<<<2048, 256, 0, stream>>>(w0, w1, w2, data, s0_0, s1_0,
                                          w0h, w0l, w1h, w1l, w2h, w2l, dh, dl,
                                          s0f[0], s1f[0], s0h[0], s0l[0], s1h[0], s1l[0],
                                          bar);

    inp1_kernel<<<512, 512, 0, stream>>>(dh, dl, w2h, w2l, partial);
    reduce_kernel<<<BATCH * N1 / 4 / 256, 256, 0, stream>>>(partial, b2, inp1);

    PP pp;
    pp.w1h = w1h; pp.w1l = w1l; pp.w0h = w0h; pp.w0l = w0l;
    pp.inp1 = inp1; pp.b0 = b0;
    pp.s0f0 = s0f[0]; pp.s0f1 = s0f[1]; pp.s1f0 = s1f[0]; pp.s1f1 = s1f[1];
    pp.s0h0 = s0h[0]; pp.s0h1 = s0h[1]; pp.s0l0 = s0l[0]; pp.s0l1 = s0l[1];
    pp.s1h0 = s1h[0]; pp.s1h1 = s1h[1]; pp.s1l0 = s1l[0]; pp.s1l1 = s1l[1];
    pp.out_s0 = (float*)d_out;
    pp.out_s1 = (float*)d_out + (size_t)BATCH * N0;
    pp.arrive = bar;
    pp.epoch  = bar + 256 * 32;

    void* args[] = { &pp };
    hipLaunchCooperativeKernel((const void*)persist_kernel,
                               dim3(256), dim3(512), args, 0, stream);
}